// Round 8
// baseline (2529.760 us; speedup 1.0000x reference)
//
#include <hip/hip_runtime.h>
#include <hip/hip_bf16.h>

using bf16 = __hip_bfloat16;
typedef __attribute__((ext_vector_type(4))) float f32x4;
typedef __attribute__((ext_vector_type(4))) int   i32x4;
typedef __attribute__((ext_vector_type(8))) int   i32x8;

#define DEVINL __device__ __forceinline__

// activations stored x16 (dequant 2^-4 -> scale byte 0x7B)
// weights    stored x64 (dequant 2^-6 -> scale byte 0x79)
#define ASCALE 16.0f
#define WSCALE 64.0f
#define SCALE_A_DW 0x7B7B7B7B
#define SCALE_B_DW 0x79797979

DEVINL float bf2f(unsigned short u) {
    bf16 b = *reinterpret_cast<bf16*>(&u);
    return __bfloat162float(b);
}
DEVINL unsigned char f2fp8(float x) {   // e4m3 (OCP), saturating
    return (unsigned char)(__builtin_amdgcn_cvt_pk_fp8_f32(x, x, 0, 0) & 0xff);
}

DEVINL void gload_lds16(const void* g, void* l) {
    __builtin_amdgcn_global_load_lds(
        (const __attribute__((address_space(1))) void*)g,
        (__attribute__((address_space(3))) void*)l,
        16, 0, 0);
}

#define BAR()   asm volatile("s_barrier" ::: "memory")
#define LGKM0() asm volatile("s_waitcnt lgkmcnt(0)" ::: "memory")

// ---------------------------------------------------------------------------
__global__ void init_acc(double* acc) {
    if (threadIdx.x < 2) acc[threadIdx.x] = 0.0;
}

// ---------------------------------------------------------------------------
// transpose + cast + scale: W[K][N] f32 -> WT[N][K] fp8 (x64)
// ---------------------------------------------------------------------------
__global__ void transpose_cast_fp8(const float* __restrict__ W,
                                   unsigned char* __restrict__ WT,
                                   int K, int N) {
    __shared__ float tile[32][33];
    int n0 = blockIdx.x * 32, k0 = blockIdx.y * 32;
    int tx = threadIdx.x, ty0 = threadIdx.y;   // block 32 x 8
#pragma unroll
    for (int i = 0; i < 4; ++i) {
        int ty = ty0 + i * 8;
        tile[ty][tx] = W[(size_t)(k0 + ty) * N + n0 + tx];
    }
    __syncthreads();
#pragma unroll
    for (int i = 0; i < 4; ++i) {
        int ty = ty0 + i * 8;
        WT[(size_t)(n0 + ty) * K + k0 + tx] = f2fp8(tile[tx][ty] * WSCALE);
    }
}

// ---------------------------------------------------------------------------
// gather sampled rows (rows <8192 come from hidden flat) -> fp8 x16 only
// ---------------------------------------------------------------------------
__global__ void gather_cast(const float* __restrict__ hidden,
                            const float* __restrict__ memory,
                            const int* __restrict__ idx,
                            unsigned char* __restrict__ samples8) {
    int s = blockIdx.x;
    int r = idx[s];
    const float* src = (r < 8192) ? hidden + (size_t)r * 4096
                                  : memory + (size_t)r * 4096;
    unsigned char* d8 = samples8 + (size_t)s * 4096;
#pragma unroll
    for (int c = threadIdx.x * 4; c < 4096; c += 1024) {
        float4 v = *(const float4*)(src + c);
        int w = __builtin_amdgcn_cvt_pk_fp8_f32(v.x * ASCALE, v.y * ASCALE, 0, 0);
        w = __builtin_amdgcn_cvt_pk_fp8_f32(v.z * ASCALE, v.w * ASCALE, w, 1);
        *(unsigned int*)(d8 + c) = (unsigned int)w;
    }
}

// ---------------------------------------------------------------------------
// MX-fp8 8-phase GEMM (R5 structure, launch_bounds(512,1) -> 256-reg budget)
// BM=BN=256, BK=128 B, 2 K-tiles/iter, 8 waves (2Mx4N), LDS 128 KiB,
// register-cached B frags (b0f/b1f live across phases -- the race-free
// ledger: buf0.B staged ph3/ph4 AFTER its last ds_read in ph2).
// EPI: 0 = gelu(exact)->fp8 x16 ; 1 = store bf16 ; 3 = MSE vs deq(s8)
// ---------------------------------------------------------------------------
template <int EPI>
__global__ __launch_bounds__(512, 1)
void gemm8p8(const unsigned char* __restrict__ A,
             const unsigned char* __restrict__ BT,
             const float* __restrict__ bias, void* __restrict__ Cout,
             const unsigned char* __restrict__ S, double* __restrict__ accum,
             int M, int N, int K, int MT) {
    __shared__ __align__(16) unsigned char lds[2][2][256 * 128];

    const int tid  = threadIdx.x;
    const int lane = tid & 63;
    const int wave = tid >> 6;      // 0..7
    const int wr   = wave >> 2;     // 0..1
    const int wc   = wave & 3;      // 0..3

    // XCD-aware bijective chunked decode (gridDim.x % 8 == 0 here)
    const int nwg  = gridDim.x;
    const int cpx  = nwg >> 3;
    const int work = (blockIdx.x & 7) * cpx + (blockIdx.x >> 3);
    const int ntile = work / MT;
    const int mtile = work - ntile * MT;
    const int m0 = mtile * 256;
    const int n0 = ntile * 256;

    const int nk2 = K >> 7;         // # K-tiles of 128 bytes

    const int srow = tid >> 3;      // 0..63
    const int skb  = tid & 7;       // 16B slot 0..7

    auto stage2 = [&](int buf, int mat, int h, int kt) {
        if (kt >= nk2) return;
        const unsigned char* G = mat ? BT : A;
        const int base0 = mat ? n0 : m0;
        const size_t kcol = (size_t)kt * 128;
#pragma unroll
        for (int j = 0; j < 2; ++j) {
            int row = h * 128 + j * 64 + srow;
            int sg  = skb ^ (row & 7);            // inverse-swizzled source
            gload_lds16(G + (size_t)(base0 + row) * K + kcol + (size_t)sg * 16,
                        &lds[buf][mat][row * 128 + skb * 16]);  // linear dest
        }
    };

    const int s0  = (lane >> 4) * 2;   // even 16B-slot index of frag start
    const int l15 = lane & 15;
    auto rdfrag = [&](const unsigned char* base, int row) -> i32x8 {
        const unsigned char* rp = base + row * 128;
        int r7 = row & 7;
        i32x4 lo = *(const i32x4*)(rp + (((s0    ) ^ r7) << 4));
        i32x4 hi = *(const i32x4*)(rp + (((s0 + 1) ^ r7) << 4));
        return __builtin_shufflevector(lo, hi, 0, 1, 2, 3, 4, 5, 6, 7);
    };
    auto rdA = [&](int buf, int mf) -> i32x8 {
        return rdfrag(lds[buf][0], wr * 128 + mf * 16 + l15);
    };
    auto rdB = [&](int buf, int nf) -> i32x8 {
        return rdfrag(lds[buf][1], wc * 64 + nf * 16 + l15);
    };

    f32x4 acc[8][4] = {};
    i32x8 af[4], b0f[2], b1f[2];

    auto mfma_quad = [&](int mh, int nh, i32x8 (&BF)[2]) {
        __builtin_amdgcn_s_setprio(1);
#pragma unroll
        for (int mi = 0; mi < 4; ++mi)
#pragma unroll
            for (int nj = 0; nj < 2; ++nj)
                acc[mh * 4 + mi][nh * 2 + nj] =
                    __builtin_amdgcn_mfma_scale_f32_16x16x128_f8f6f4(
                        af[mi], BF[nj], acc[mh * 4 + mi][nh * 2 + nj],
                        0, 0,                       // cbsz=fp8, blgp=fp8
                        0, SCALE_A_DW, 0, SCALE_B_DW);
        __builtin_amdgcn_s_setprio(0);
    };

    // ---- prologue: buf0 = tile0 (B,A), buf1 = tile1 (B only) = 12 loads
    stage2(0, 1, 0, 0); stage2(0, 1, 1, 0);
    stage2(0, 0, 0, 0); stage2(0, 0, 1, 0);
    stage2(1, 1, 0, 1); stage2(1, 1, 1, 1);
    asm volatile("s_waitcnt vmcnt(4)\n\ts_barrier" ::: "memory");  // buf0 landed

    const int niter = nk2 >> 1;
    for (int it = 0; it < niter; ++it) {
        const int ta = 2 * it, tb = 2 * it + 1;
        const bool last = (it == niter - 1);

        // ---- ph1 ----
#pragma unroll
        for (int mi = 0; mi < 4; ++mi) af[mi] = rdA(0, mi);
#pragma unroll
        for (int nj = 0; nj < 2; ++nj) b0f[nj] = rdB(0, nj);
        stage2(1, 0, 0, tb);
        asm volatile("s_waitcnt lgkmcnt(8)" :::);
        BAR(); LGKM0();
        mfma_quad(0, 0, b0f);
        BAR();
        // ---- ph2 ----
#pragma unroll
        for (int nj = 0; nj < 2; ++nj) b1f[nj] = rdB(0, nj + 2);
        stage2(1, 0, 1, tb);
        BAR(); LGKM0();
        mfma_quad(0, 1, b1f);
        BAR();
        // ---- ph3 ----
#pragma unroll
        for (int mi = 0; mi < 4; ++mi) af[mi] = rdA(0, mi + 4);
        stage2(0, 1, 0, ta + 2);
        BAR(); LGKM0();
        mfma_quad(1, 0, b0f);
        BAR();
        // ---- ph4 ----
        stage2(0, 1, 1, ta + 2);
        BAR(); LGKM0();
        mfma_quad(1, 1, b1f);
        if (last) asm volatile("s_waitcnt vmcnt(0)\n\ts_barrier" ::: "memory");
        else      asm volatile("s_waitcnt vmcnt(4)\n\ts_barrier" ::: "memory");
        // ---- ph5 ----
#pragma unroll
        for (int mi = 0; mi < 4; ++mi) af[mi] = rdA(1, mi);
#pragma unroll
        for (int nj = 0; nj < 2; ++nj) b0f[nj] = rdB(1, nj);
        stage2(0, 0, 0, ta + 2);
        asm volatile("s_waitcnt lgkmcnt(8)" :::);
        BAR(); LGKM0();
        mfma_quad(0, 0, b0f);
        BAR();
        // ---- ph6 ----
#pragma unroll
        for (int nj = 0; nj < 2; ++nj) b1f[nj] = rdB(1, nj + 2);
        stage2(0, 0, 1, ta + 2);
        BAR(); LGKM0();
        mfma_quad(0, 1, b1f);
        BAR();
        // ---- ph7 ----
#pragma unroll
        for (int mi = 0; mi < 4; ++mi) af[mi] = rdA(1, mi + 4);
        stage2(1, 1, 0, tb + 2);
        BAR(); LGKM0();
        mfma_quad(1, 0, b0f);
        BAR();
        // ---- ph8 ----
        stage2(1, 1, 1, tb + 2);
        BAR(); LGKM0();
        mfma_quad(1, 1, b1f);
        if (!last)
            asm volatile("s_waitcnt vmcnt(4)\n\ts_barrier" ::: "memory");
    }

    // epilogue: C/D layout col=lane&15, row=(lane>>4)*4+j  [m89-verified]
    float lsum = 0.f;
#pragma unroll
    for (int m = 0; m < 8; ++m) {
        int row0 = m0 + wr * 128 + m * 16 + (lane >> 4) * 4;
#pragma unroll
        for (int n = 0; n < 4; ++n) {
            int col = n0 + wc * 64 + n * 16 + l15;
            float bv = bias[col];
#pragma unroll
            for (int j = 0; j < 4; ++j) {
                float v  = acc[m][n][j] + bv;
                int row  = row0 + j;
                if (EPI == 0) {
                    float ge = 0.5f * v * (1.f + erff(v * 0.70710678118f));
                    ((unsigned char*)Cout)[(size_t)row * N + col] =
                        f2fp8(ge * ASCALE);
                } else if (EPI == 1) {
                    ((bf16*)Cout)[(size_t)row * N + col] = __float2bfloat16(v);
                } else {
                    unsigned int sb = S[(size_t)row * N + col];
                    float sv = __builtin_amdgcn_cvt_f32_fp8(sb, 0) * (1.0f / ASCALE);
                    float d = v - sv;
                    lsum += d * d;
                }
            }
        }
    }

    if (EPI == 3) {
        __shared__ float red[8];
        float v = lsum;
#pragma unroll
        for (int o = 32; o > 0; o >>= 1) v += __shfl_down(v, o);
        if (lane == 0) red[wave] = v;
        __syncthreads();
        if (tid == 0) {
            double t = 0.0;
#pragma unroll
            for (int w = 0; w < 8; ++w) t += (double)red[w];
            atomicAdd(accum, t);
        }
    }
}

// ---------------------------------------------------------------------------
// reparameterization + KL partial sums; z written as fp8 x16 for GEMM3
// ---------------------------------------------------------------------------
__global__ void z_kl_kernel(const bf16* __restrict__ enc,
                            const float* __restrict__ eps,
                            unsigned char* __restrict__ z,
                            double* __restrict__ acc) {
    int s = blockIdx.x;
    int c = threadIdx.x * 4;
    ushort4 muu = *(const ushort4*)((const unsigned short*)(enc + (size_t)s * 2048 + c));
    ushort4 lvu = *(const ushort4*)((const unsigned short*)(enc + (size_t)s * 2048 + 1024 + c));
    float4 ev   = *(const float4*)(eps + (size_t)s * 1024 + c);

    float kl = 0.f;
    float z0, z1, z2, z3;
    {
        float mu = bf2f(muu.x), lv = bf2f(lvu.x), el = expf(lv);
        z0 = mu + sqrtf(el) * ev.x;
        kl += 1.f + lv - mu * mu - el;
    }
    {
        float mu = bf2f(muu.y), lv = bf2f(lvu.y), el = expf(lv);
        z1 = mu + sqrtf(el) * ev.y;
        kl += 1.f + lv - mu * mu - el;
    }
    {
        float mu = bf2f(muu.z), lv = bf2f(lvu.z), el = expf(lv);
        z2 = mu + sqrtf(el) * ev.z;
        kl += 1.f + lv - mu * mu - el;
    }
    {
        float mu = bf2f(muu.w), lv = bf2f(lvu.w), el = expf(lv);
        z3 = mu + sqrtf(el) * ev.w;
        kl += 1.f + lv - mu * mu - el;
    }
    int w = __builtin_amdgcn_cvt_pk_fp8_f32(z0 * ASCALE, z1 * ASCALE, 0, 0);
    w = __builtin_amdgcn_cvt_pk_fp8_f32(z2 * ASCALE, z3 * ASCALE, w, 1);
    *(unsigned int*)(z + (size_t)s * 1024 + c) = (unsigned int)w;

    __shared__ float red[4];
    float v = kl;
#pragma unroll
    for (int o = 32; o > 0; o >>= 1) v += __shfl_down(v, o);
    int lane = threadIdx.x & 63, wv = threadIdx.x >> 6;
    if (lane == 0) red[wv] = v;
    __syncthreads();
    if (threadIdx.x == 0) {
        double t = (double)red[0] + (double)red[1] +
                   (double)red[2] + (double)red[3];
        atomicAdd(acc + 1, t);
    }
}

// ---------------------------------------------------------------------------
__global__ void finalize_kernel(const double* __restrict__ acc,
                                float* __restrict__ out) {
    if (threadIdx.x == 0)
        out[0] = (float)(acc[0] * (1.0 / (16384.0 * 4096.0)) - 0.0005 * acc[1]);
}

// ---------------------------------------------------------------------------
extern "C" void kernel_launch(void* const* d_in, const int* in_sizes, int n_in,
                              void* d_out, int out_size, void* d_ws, size_t ws_size,
                              hipStream_t stream) {
    const float* hidden = (const float*)d_in[0];
    const float* memory = (const float*)d_in[1];
    const int*   idx    = (const int*)d_in[2];
    const float* eps    = (const float*)d_in[3];
    const float* W1     = (const float*)d_in[4];
    const float* b1     = (const float*)d_in[5];
    const float* W2     = (const float*)d_in[6];
    const float* b2     = (const float*)d_in[7];
    const float* Wd1    = (const float*)d_in[8];
    const float* bd1    = (const float*)d_in[9];
    const float* Wd2    = (const float*)d_in[10];
    const float* bd2    = (const float*)d_in[11];

    char* ws = (char*)d_ws;
    double* acc            = (double*)ws;                            // 256 B
    unsigned char* s8      = (unsigned char*)(ws + 256);             // 67 MB
    unsigned char* h8      = s8   + (size_t)16384 * 4096;            // 33.6 MB
    bf16* enc              = (bf16*)(h8 + (size_t)16384 * 2048);     // 67 MB
    unsigned char* z8      = (unsigned char*)(enc + (size_t)16384 * 2048);
    unsigned char* hd8     = z8   + (size_t)16384 * 1024;            // 33.6 MB
    unsigned char* W1T     = hd8  + (size_t)16384 * 2048;
    unsigned char* W2T     = W1T  + (size_t)2048 * 4096;
    unsigned char* Wd1T    = W2T  + (size_t)2048 * 2048;
    unsigned char* Wd2T    = Wd1T + (size_t)2048 * 1024;

    init_acc<<<1, 64, 0, stream>>>(acc);

    dim3 tb(32, 8);
    transpose_cast_fp8<<<dim3(2048 / 32, 4096 / 32), tb, 0, stream>>>(W1, W1T, 4096, 2048);
    transpose_cast_fp8<<<dim3(2048 / 32, 2048 / 32), tb, 0, stream>>>(W2, W2T, 2048, 2048);
    transpose_cast_fp8<<<dim3(2048 / 32, 1024 / 32), tb, 0, stream>>>(Wd1, Wd1T, 1024, 2048);
    transpose_cast_fp8<<<dim3(4096 / 32, 2048 / 32), tb, 0, stream>>>(Wd2, Wd2T, 2048, 4096);

    gather_cast<<<16384, 256, 0, stream>>>(hidden, memory, idx, s8);

    // h = gelu(samples @ W1 + b1)          M=16384 N=2048 K=4096
    gemm8p8<0><<<512, 512, 0, stream>>>(s8, W1T, b1, h8, nullptr, nullptr,
                                        16384, 2048, 4096, 64);
    // enc = h @ W2 + b2                    K=2048
    gemm8p8<1><<<512, 512, 0, stream>>>(h8, W2T, b2, enc, nullptr, nullptr,
                                        16384, 2048, 2048, 64);
    // z = mu + exp(0.5 lv) * eps ; kl partials ; z -> fp8 x16
    z_kl_kernel<<<16384, 256, 0, stream>>>(enc, eps, z8, acc);
    // hd = gelu(z @ Wd1 + bd1)             K=1024
    gemm8p8<0><<<512, 512, 0, stream>>>(z8, Wd1T, bd1, hd8, nullptr, nullptr,
                                        16384, 2048, 1024, 64);
    // rec = hd @ Wd2 + bd2 ; fused recon MSE vs deq(s8)   N=4096 K=2048
    gemm8p8<3><<<1024, 512, 0, stream>>>(hd8, Wd2T, bd2, nullptr, s8, acc,
                                         16384, 4096, 2048, 64);

    finalize_kernel<<<1, 64, 0, stream>>>(acc, (float*)d_out);
}

// Round 9
// 851.996 us; speedup vs baseline: 2.9692x; 2.9692x over previous
//
#include <hip/hip_runtime.h>
#include <hip/hip_bf16.h>

using bf16 = __hip_bfloat16;
typedef __attribute__((ext_vector_type(16))) float f32x16;
typedef __attribute__((ext_vector_type(4)))  int   i32x4;
typedef __attribute__((ext_vector_type(8)))  int   i32x8;

#define DEVINL __device__ __forceinline__

// activations stored x16 (dequant 2^-4 -> scale byte 0x7B)
// weights    stored x64 (dequant 2^-6 -> scale byte 0x79)
#define ASCALE 16.0f
#define WSCALE 64.0f
#define SCALE_A_DW 0x7B7B7B7B
#define SCALE_B_DW 0x79797979

DEVINL float bf2f(unsigned short u) {
    bf16 b = *reinterpret_cast<bf16*>(&u);
    return __bfloat162float(b);
}
DEVINL unsigned char f2fp8(float x) {   // e4m3 (OCP), saturating
    return (unsigned char)(__builtin_amdgcn_cvt_pk_fp8_f32(x, x, 0, 0) & 0xff);
}

DEVINL void gload_lds16(const void* g, void* l) {
    __builtin_amdgcn_global_load_lds(
        (const __attribute__((address_space(1))) void*)g,
        (__attribute__((address_space(3))) void*)l,
        16, 0, 0);
}

// ---------------------------------------------------------------------------
__global__ void init_acc(double* acc) {
    if (threadIdx.x < 2) acc[threadIdx.x] = 0.0;
}

// ---------------------------------------------------------------------------
// transpose + cast + scale: W[K][N] f32 -> WT[N][K] fp8 (x64)
// ---------------------------------------------------------------------------
__global__ void transpose_cast_fp8(const float* __restrict__ W,
                                   unsigned char* __restrict__ WT,
                                   int K, int N) {
    __shared__ float tile[32][33];
    int n0 = blockIdx.x * 32, k0 = blockIdx.y * 32;
    int tx = threadIdx.x, ty0 = threadIdx.y;   // block 32 x 8
#pragma unroll
    for (int i = 0; i < 4; ++i) {
        int ty = ty0 + i * 8;
        tile[ty][tx] = W[(size_t)(k0 + ty) * N + n0 + tx];
    }
    __syncthreads();
#pragma unroll
    for (int i = 0; i < 4; ++i) {
        int ty = ty0 + i * 8;
        WT[(size_t)(n0 + ty) * K + k0 + tx] = f2fp8(tile[tx][ty] * WSCALE);
    }
}

// ---------------------------------------------------------------------------
// gather sampled rows (rows <8192 come from hidden flat) -> fp8 x16
// ---------------------------------------------------------------------------
__global__ void gather_cast(const float* __restrict__ hidden,
                            const float* __restrict__ memory,
                            const int* __restrict__ idx,
                            unsigned char* __restrict__ samples8) {
    int s = blockIdx.x;
    int r = idx[s];
    const float* src = (r < 8192) ? hidden + (size_t)r * 4096
                                  : memory + (size_t)r * 4096;
    unsigned char* d8 = samples8 + (size_t)s * 4096;
#pragma unroll
    for (int c = threadIdx.x * 4; c < 4096; c += 1024) {
        float4 v = *(const float4*)(src + c);
        int w = __builtin_amdgcn_cvt_pk_fp8_f32(v.x * ASCALE, v.y * ASCALE, 0, 0);
        w = __builtin_amdgcn_cvt_pk_fp8_f32(v.z * ASCALE, v.w * ASCALE, w, 1);
        *(unsigned int*)(d8 + c) = (unsigned int)w;
    }
}

// ---------------------------------------------------------------------------
// MX-fp8 GEMM, R7 geometry + 32x32x64 MFMA (2x FLOP per LDS byte):
// 128x128 tile, BK=128 B (2 MFMA k-substeps), 4 waves (2x2), double-buffered
// LDS 64 KiB -> 2 blocks/CU. Per wave: 64x64 output = f32x16 acc[2][2]
// (64 f32 -- R7's proven no-spill footprint). Stage path identical to R7
// (8 x 16B slots/row, ^(row&7) swizzle, linear LDS dest, pre-swz source).
// Frag (32x32x64): row = lane&31, k-chunk (lane>>5)*32 within the 64B
// k-substep -> two swizzled b128; uniform 8 lanes/bank-group (minimal).
// C/D 32x32 map [m101]: col=lane&31, row=(reg&3)+8*(reg>>2)+4*(lane>>5).
// EPI: 0 = gelu(exact)->fp8 x16 ; 1 = store bf16 ; 3 = MSE vs deq(s8)
// ---------------------------------------------------------------------------
template <int EPI>
__global__ __launch_bounds__(256, 2)
void gemm128f8(const unsigned char* __restrict__ A,
               const unsigned char* __restrict__ BT,
               const float* __restrict__ bias, void* __restrict__ Cout,
               const unsigned char* __restrict__ S, double* __restrict__ accum,
               int M, int N, int K, int MT) {
    __shared__ __align__(16) unsigned char lds[2][2][128 * 128];

    const int tid  = threadIdx.x;
    const int lane = tid & 63;
    const int wave = tid >> 6;      // 0..3
    const int wr   = wave >> 1;     // 0..1
    const int wc   = wave & 1;      // 0..1

    // XCD-aware bijective chunked decode (gridDim.x % 8 == 0 here)
    const int nwg  = gridDim.x;
    const int cpx  = nwg >> 3;
    const int work = (blockIdx.x & 7) * cpx + (blockIdx.x >> 3);
    const int ntile = work / MT;
    const int mtile = work - ntile * MT;
    const int m0 = mtile * 128;
    const int n0 = ntile * 128;

    const int nk = K >> 7;          // # K-steps of 128 bytes

    const int srow = tid >> 3;      // 0..31
    const int skb  = tid & 7;       // 16B slot 0..7

    auto stage = [&](int buf, int kt) {
        const size_t kcol = (size_t)kt * 128;
#pragma unroll
        for (int mat = 0; mat < 2; ++mat) {
            const unsigned char* G = mat ? BT : A;
            const int base0 = mat ? n0 : m0;
#pragma unroll
            for (int j = 0; j < 4; ++j) {
                int row = j * 32 + srow;
                int sg  = skb ^ (row & 7);        // inverse-swizzled source
                gload_lds16(G + (size_t)(base0 + row) * K + kcol + (size_t)sg * 16,
                            &lds[buf][mat][row * 128 + skb * 16]);  // linear dest
            }
        }
    };

    const int g32 = (lane >> 5);       // k-chunk group (0..1)
    const int l31 = lane & 31;
    auto rdfrag = [&](const unsigned char* base, int row, int ks) -> i32x8 {
        const unsigned char* rp = base + row * 128;
        int r7 = row & 7;
        int s0 = ks * 4 + g32 * 2;
        i32x4 lo = *(const i32x4*)(rp + (((s0    ) ^ r7) << 4));
        i32x4 hi = *(const i32x4*)(rp + (((s0 + 1) ^ r7) << 4));
        return __builtin_shufflevector(lo, hi, 0, 1, 2, 3, 4, 5, 6, 7);
    };

    f32x16 acc[2][2] = {};

    stage(0, 0);
    __syncthreads();
    int cur = 0;
    for (int t = 0; t < nk; ++t) {
        if (t + 1 < nk) stage(cur ^ 1, t + 1);
#pragma unroll
        for (int ks = 0; ks < 2; ++ks) {
            i32x8 a0 = rdfrag(lds[cur][0], wr * 64 +  0 + l31, ks);
            i32x8 a1 = rdfrag(lds[cur][0], wr * 64 + 32 + l31, ks);
            i32x8 b0 = rdfrag(lds[cur][1], wc * 64 +  0 + l31, ks);
            i32x8 b1 = rdfrag(lds[cur][1], wc * 64 + 32 + l31, ks);
            acc[0][0] = __builtin_amdgcn_mfma_scale_f32_32x32x64_f8f6f4(
                a0, b0, acc[0][0], 0, 0, 0, SCALE_A_DW, 0, SCALE_B_DW);
            acc[0][1] = __builtin_amdgcn_mfma_scale_f32_32x32x64_f8f6f4(
                a0, b1, acc[0][1], 0, 0, 0, SCALE_A_DW, 0, SCALE_B_DW);
            acc[1][0] = __builtin_amdgcn_mfma_scale_f32_32x32x64_f8f6f4(
                a1, b0, acc[1][0], 0, 0, 0, SCALE_A_DW, 0, SCALE_B_DW);
            acc[1][1] = __builtin_amdgcn_mfma_scale_f32_32x32x64_f8f6f4(
                a1, b1, acc[1][1], 0, 0, 0, SCALE_A_DW, 0, SCALE_B_DW);
        }
        __syncthreads();
        cur ^= 1;
    }

    // epilogue: 32x32 C/D map col=lane&31, row=(reg&3)+8*(reg>>2)+4*(lane>>5)
    float lsum = 0.f;
#pragma unroll
    for (int fr = 0; fr < 2; ++fr) {
#pragma unroll
        for (int fc = 0; fc < 2; ++fc) {
            int colg = n0 + wc * 64 + fc * 32 + l31;
            float bv = bias[colg];
#pragma unroll
            for (int reg = 0; reg < 16; ++reg) {
                int row = m0 + wr * 64 + fr * 32 +
                          (reg & 3) + 8 * (reg >> 2) + 4 * g32;
                float v = acc[fr][fc][reg] + bv;
                if (EPI == 0) {
                    float ge = 0.5f * v * (1.f + erff(v * 0.70710678118f));
                    ((unsigned char*)Cout)[(size_t)row * N + colg] =
                        f2fp8(ge * ASCALE);
                } else if (EPI == 1) {
                    ((bf16*)Cout)[(size_t)row * N + colg] = __float2bfloat16(v);
                } else {
                    unsigned int sb = S[(size_t)row * N + colg];
                    float sv = __builtin_amdgcn_cvt_f32_fp8(sb, 0) * (1.0f / ASCALE);
                    float d = v - sv;
                    lsum += d * d;
                }
            }
        }
    }

    if (EPI == 3) {
        __shared__ float red[4];
        float v = lsum;
#pragma unroll
        for (int o = 32; o > 0; o >>= 1) v += __shfl_down(v, o);
        if (lane == 0) red[wave] = v;
        __syncthreads();
        if (tid == 0) {
            double t = (double)red[0] + (double)red[1] +
                       (double)red[2] + (double)red[3];
            atomicAdd(accum, t);
        }
    }
}

// ---------------------------------------------------------------------------
// reparameterization + KL partial sums; z written as fp8 x16 for GEMM3
// ---------------------------------------------------------------------------
__global__ void z_kl_kernel(const bf16* __restrict__ enc,
                            const float* __restrict__ eps,
                            unsigned char* __restrict__ z,
                            double* __restrict__ acc) {
    int s = blockIdx.x;
    int c = threadIdx.x * 4;
    ushort4 muu = *(const ushort4*)((const unsigned short*)(enc + (size_t)s * 2048 + c));
    ushort4 lvu = *(const ushort4*)((const unsigned short*)(enc + (size_t)s * 2048 + 1024 + c));
    float4 ev   = *(const float4*)(eps + (size_t)s * 1024 + c);

    float kl = 0.f;
    float z0, z1, z2, z3;
    {
        float mu = bf2f(muu.x), lv = bf2f(lvu.x), el = expf(lv);
        z0 = mu + sqrtf(el) * ev.x;
        kl += 1.f + lv - mu * mu - el;
    }
    {
        float mu = bf2f(muu.y), lv = bf2f(lvu.y), el = expf(lv);
        z1 = mu + sqrtf(el) * ev.y;
        kl += 1.f + lv - mu * mu - el;
    }
    {
        float mu = bf2f(muu.z), lv = bf2f(lvu.z), el = expf(lv);
        z2 = mu + sqrtf(el) * ev.z;
        kl += 1.f + lv - mu * mu - el;
    }
    {
        float mu = bf2f(muu.w), lv = bf2f(lvu.w), el = expf(lv);
        z3 = mu + sqrtf(el) * ev.w;
        kl += 1.f + lv - mu * mu - el;
    }
    int w = __builtin_amdgcn_cvt_pk_fp8_f32(z0 * ASCALE, z1 * ASCALE, 0, 0);
    w = __builtin_amdgcn_cvt_pk_fp8_f32(z2 * ASCALE, z3 * ASCALE, w, 1);
    *(unsigned int*)(z + (size_t)s * 1024 + c) = (unsigned int)w;

    __shared__ float red[4];
    float v = kl;
#pragma unroll
    for (int o = 32; o > 0; o >>= 1) v += __shfl_down(v, o);
    int lane = threadIdx.x & 63, wv = threadIdx.x >> 6;
    if (lane == 0) red[wv] = v;
    __syncthreads();
    if (threadIdx.x == 0) {
        double t = (double)red[0] + (double)red[1] +
                   (double)red[2] + (double)red[3];
        atomicAdd(acc + 1, t);
    }
}

// ---------------------------------------------------------------------------
__global__ void finalize_kernel(const double* __restrict__ acc,
                                float* __restrict__ out) {
    if (threadIdx.x == 0)
        out[0] = (float)(acc[0] * (1.0 / (16384.0 * 4096.0)) - 0.0005 * acc[1]);
}

// ---------------------------------------------------------------------------
extern "C" void kernel_launch(void* const* d_in, const int* in_sizes, int n_in,
                              void* d_out, int out_size, void* d_ws, size_t ws_size,
                              hipStream_t stream) {
    const float* hidden = (const float*)d_in[0];
    const float* memory = (const float*)d_in[1];
    const int*   idx    = (const int*)d_in[2];
    const float* eps    = (const float*)d_in[3];
    const float* W1     = (const float*)d_in[4];
    const float* b1     = (const float*)d_in[5];
    const float* W2     = (const float*)d_in[6];
    const float* b2     = (const float*)d_in[7];
    const float* Wd1    = (const float*)d_in[8];
    const float* bd1    = (const float*)d_in[9];
    const float* Wd2    = (const float*)d_in[10];
    const float* bd2    = (const float*)d_in[11];

    char* ws = (char*)d_ws;
    double* acc            = (double*)ws;                            // 256 B
    unsigned char* s8      = (unsigned char*)(ws + 256);             // 67 MB
    unsigned char* h8      = s8   + (size_t)16384 * 4096;            // 33.6 MB
    bf16* enc              = (bf16*)(h8 + (size_t)16384 * 2048);     // 67 MB
    unsigned char* z8      = (unsigned char*)(enc + (size_t)16384 * 2048);
    unsigned char* hd8     = z8   + (size_t)16384 * 1024;            // 33.6 MB
    unsigned char* W1T     = hd8  + (size_t)16384 * 2048;
    unsigned char* W2T     = W1T  + (size_t)2048 * 4096;
    unsigned char* Wd1T    = W2T  + (size_t)2048 * 2048;
    unsigned char* Wd2T    = Wd1T + (size_t)2048 * 1024;

    init_acc<<<1, 64, 0, stream>>>(acc);

    dim3 tb(32, 8);
    transpose_cast_fp8<<<dim3(2048 / 32, 4096 / 32), tb, 0, stream>>>(W1, W1T, 4096, 2048);
    transpose_cast_fp8<<<dim3(2048 / 32, 2048 / 32), tb, 0, stream>>>(W2, W2T, 2048, 2048);
    transpose_cast_fp8<<<dim3(2048 / 32, 1024 / 32), tb, 0, stream>>>(Wd1, Wd1T, 1024, 2048);
    transpose_cast_fp8<<<dim3(4096 / 32, 2048 / 32), tb, 0, stream>>>(Wd2, Wd2T, 2048, 4096);

    gather_cast<<<16384, 256, 0, stream>>>(hidden, memory, idx, s8);

    // h = gelu(samples @ W1 + b1)          M=16384 N=2048 K=4096
    gemm128f8<0><<<2048, 256, 0, stream>>>(s8, W1T, b1, h8, nullptr, nullptr,
                                           16384, 2048, 4096, 128);
    // enc = h @ W2 + b2                    K=2048
    gemm128f8<1><<<2048, 256, 0, stream>>>(h8, W2T, b2, enc, nullptr, nullptr,
                                           16384, 2048, 2048, 128);
    // z = mu + exp(0.5 lv) * eps ; kl partials ; z -> fp8 x16
    z_kl_kernel<<<16384, 256, 0, stream>>>(enc, eps, z8, acc);
    // hd = gelu(z @ Wd1 + bd1)             K=1024
    gemm128f8<0><<<2048, 256, 0, stream>>>(z8, Wd1T, bd1, hd8, nullptr, nullptr,
                                           16384, 2048, 1024, 128);
    // rec = hd @ Wd2 + bd2 ; fused recon MSE vs deq(s8)   N=4096 K=2048
    gemm128f8<3><<<4096, 256, 0, stream>>>(hd8, Wd2T, bd2, nullptr, s8, acc,
                                           16384, 4096, 2048, 128);

    finalize_kernel<<<1, 64, 0, stream>>>(acc, (float*)d_out);
}

// Round 10
// 692.793 us; speedup vs baseline: 3.6515x; 1.2298x over previous
//
#include <hip/hip_runtime.h>
#include <hip/hip_bf16.h>

using bf16 = __hip_bfloat16;
typedef __attribute__((ext_vector_type(16))) float f32x16;
typedef __attribute__((ext_vector_type(4)))  int   i32x4;
typedef __attribute__((ext_vector_type(8)))  int   i32x8;

#define DEVINL __device__ __forceinline__

// activations stored x16 (dequant 2^-4 -> scale byte 0x7B)
// weights    stored x64 (dequant 2^-6 -> scale byte 0x79)
#define ASCALE 16.0f
#define WSCALE 64.0f
#define SCALE_A_DW 0x7B7B7B7B
#define SCALE_B_DW 0x79797979

DEVINL unsigned char f2fp8(float x) {   // e4m3 (OCP), saturating
    return (unsigned char)(__builtin_amdgcn_cvt_pk_fp8_f32(x, x, 0, 0) & 0xff);
}

DEVINL void gload_lds16(const void* g, void* l) {
    __builtin_amdgcn_global_load_lds(
        (const __attribute__((address_space(1))) void*)g,
        (__attribute__((address_space(3))) void*)l,
        16, 0, 0);
}

// ---------------------------------------------------------------------------
__global__ void init_acc(double* acc) {
    if (threadIdx.x < 2) acc[threadIdx.x] = 0.0;
}

// ---------------------------------------------------------------------------
// transpose + cast + scale: W[K][N] f32 -> WT[g(N)][K] fp8 (x64)
// interleave=1 (for W2): out row g(c) = c<1024 ? 2c : 2(c-1024)+1, so that
// WT rows alternate mu-col / lv-col -- GEMM2 epilogue pairs them by lane^1.
// ---------------------------------------------------------------------------
__global__ void transpose_cast_fp8(const float* __restrict__ W,
                                   unsigned char* __restrict__ WT,
                                   int K, int N, int interleave) {
    __shared__ float tile[32][33];
    int n0 = blockIdx.x * 32, k0 = blockIdx.y * 32;
    int tx = threadIdx.x, ty0 = threadIdx.y;   // block 32 x 8
#pragma unroll
    for (int i = 0; i < 4; ++i) {
        int ty = ty0 + i * 8;
        tile[ty][tx] = W[(size_t)(k0 + ty) * N + n0 + tx];
    }
    __syncthreads();
#pragma unroll
    for (int i = 0; i < 4; ++i) {
        int ty = ty0 + i * 8;
        int src = n0 + ty;
        int orow = interleave ? ((src < 1024) ? 2 * src : 2 * (src - 1024) + 1)
                              : src;
        WT[(size_t)orow * K + k0 + tx] = f2fp8(tile[tx][ty] * WSCALE);
    }
}

// ---------------------------------------------------------------------------
// gather sampled rows (rows <8192 come from hidden flat) -> fp8 x16
// ---------------------------------------------------------------------------
__global__ void gather_cast(const float* __restrict__ hidden,
                            const float* __restrict__ memory,
                            const int* __restrict__ idx,
                            unsigned char* __restrict__ samples8) {
    int s = blockIdx.x;
    int r = idx[s];
    const float* src = (r < 8192) ? hidden + (size_t)r * 4096
                                  : memory + (size_t)r * 4096;
    unsigned char* d8 = samples8 + (size_t)s * 4096;
#pragma unroll
    for (int c = threadIdx.x * 4; c < 4096; c += 1024) {
        float4 v = *(const float4*)(src + c);
        int w = __builtin_amdgcn_cvt_pk_fp8_f32(v.x * ASCALE, v.y * ASCALE, 0, 0);
        w = __builtin_amdgcn_cvt_pk_fp8_f32(v.z * ASCALE, v.w * ASCALE, w, 1);
        *(unsigned int*)(d8 + c) = (unsigned int)w;
    }
}

// ---------------------------------------------------------------------------
// MX-fp8 GEMM, m97 occupancy recipe: 128x128 tile, BK=64 B (one 32x32x64
// k-substep), 4 waves (2x2), double-buffered LDS 32 KiB -> 4-5 blocks/CU
// (cross-block overlap hides the per-step vmcnt drain). Swizzle skb^(row&3)
// over 4x16B slots, both sides (2-way bank aliasing = free, m136).
// Per wave: 64x64 out = f32x16 acc[2][2] (64 f32, no spill -- R7-proven).
// C/D 32x32 map [m101]: col=lane&31, row=(reg&3)+8*(reg>>2)+4*(lane>>5).
// EPI: 0 = gelu(exact)->fp8 x16
//      2 = fused reparam: interleaved (mu,lv) cols -> z fp8 + KL partials
//      3 = recon MSE vs deq(s8)
// ---------------------------------------------------------------------------
template <int EPI>
__global__ __launch_bounds__(256, 4)
void gemm128f8(const unsigned char* __restrict__ A,
               const unsigned char* __restrict__ BT,
               const float* __restrict__ bias, void* __restrict__ Cout,
               const unsigned char* __restrict__ S,
               const float* __restrict__ EPS, double* __restrict__ accum,
               int M, int N, int K, int MT) {
    __shared__ __align__(16) unsigned char lds[2][2][128 * 64];

    const int tid  = threadIdx.x;
    const int lane = tid & 63;
    const int wave = tid >> 6;      // 0..3
    const int wr   = wave >> 1;     // 0..1
    const int wc   = wave & 1;      // 0..1

    // XCD-aware bijective chunked decode (gridDim.x % 8 == 0 here)
    const int nwg  = gridDim.x;
    const int cpx  = nwg >> 3;
    const int work = (blockIdx.x & 7) * cpx + (blockIdx.x >> 3);
    const int ntile = work / MT;
    const int mtile = work - ntile * MT;
    const int m0 = mtile * 128;
    const int n0 = ntile * 128;

    const int nk = K >> 6;          // # K-steps of 64 bytes

    const int srow = tid >> 2;      // 0..63
    const int skb  = tid & 3;       // 16B slot 0..3

    auto stage = [&](int buf, int kt) {
        const size_t kcol = (size_t)kt * 64;
#pragma unroll
        for (int mat = 0; mat < 2; ++mat) {
            const unsigned char* G = mat ? BT : A;
            const int base0 = mat ? n0 : m0;
#pragma unroll
            for (int j = 0; j < 2; ++j) {
                int row = j * 64 + srow;
                int sg  = skb ^ (row & 3);        // inverse-swizzled source
                gload_lds16(G + (size_t)(base0 + row) * K + kcol + (size_t)sg * 16,
                            &lds[buf][mat][row * 64 + skb * 16]);  // linear dest
            }
        }
    };

    const int g32 = (lane >> 5);       // k-chunk group (0..1)
    const int l31 = lane & 31;
    auto rdfrag = [&](const unsigned char* base, int row) -> i32x8 {
        const unsigned char* rp = base + row * 64;
        int r3 = row & 3;
        int s0 = g32 * 2;
        i32x4 lo = *(const i32x4*)(rp + (((s0    ) ^ r3) << 4));
        i32x4 hi = *(const i32x4*)(rp + (((s0 + 1) ^ r3) << 4));
        return __builtin_shufflevector(lo, hi, 0, 1, 2, 3, 4, 5, 6, 7);
    };

    f32x16 acc[2][2] = {};

    stage(0, 0);
    __syncthreads();
    int cur = 0;
    for (int t = 0; t < nk; ++t) {
        if (t + 1 < nk) stage(cur ^ 1, t + 1);
        i32x8 a0 = rdfrag(lds[cur][0], wr * 64 +  0 + l31);
        i32x8 a1 = rdfrag(lds[cur][0], wr * 64 + 32 + l31);
        i32x8 b0 = rdfrag(lds[cur][1], wc * 64 +  0 + l31);
        i32x8 b1 = rdfrag(lds[cur][1], wc * 64 + 32 + l31);
        acc[0][0] = __builtin_amdgcn_mfma_scale_f32_32x32x64_f8f6f4(
            a0, b0, acc[0][0], 0, 0, 0, SCALE_A_DW, 0, SCALE_B_DW);
        acc[0][1] = __builtin_amdgcn_mfma_scale_f32_32x32x64_f8f6f4(
            a0, b1, acc[0][1], 0, 0, 0, SCALE_A_DW, 0, SCALE_B_DW);
        acc[1][0] = __builtin_amdgcn_mfma_scale_f32_32x32x64_f8f6f4(
            a1, b0, acc[1][0], 0, 0, 0, SCALE_A_DW, 0, SCALE_B_DW);
        acc[1][1] = __builtin_amdgcn_mfma_scale_f32_32x32x64_f8f6f4(
            a1, b1, acc[1][1], 0, 0, 0, SCALE_A_DW, 0, SCALE_B_DW);
        __syncthreads();
        cur ^= 1;
    }

    // epilogue: 32x32 C/D map col=lane&31, row=(reg&3)+8*(reg>>2)+4*(lane>>5)
    float lsum = 0.f;
#pragma unroll
    for (int fr = 0; fr < 2; ++fr) {
#pragma unroll
        for (int fc = 0; fc < 2; ++fc) {
            int colg = n0 + wc * 64 + fc * 32 + l31;
            float bv;
            if (EPI == 2)
                bv = (colg & 1) ? bias[1024 + (colg >> 1)] : bias[colg >> 1];
            else
                bv = bias[colg];
#pragma unroll
            for (int reg = 0; reg < 16; ++reg) {
                int row = m0 + wr * 64 + fr * 32 +
                          (reg & 3) + 8 * (reg >> 2) + 4 * g32;
                float v = acc[fr][fc][reg] + bv;
                if (EPI == 0) {
                    float ge = 0.5f * v * (1.f + erff(v * 0.70710678118f));
                    ((unsigned char*)Cout)[(size_t)row * N + colg] =
                        f2fp8(ge * ASCALE);
                } else if (EPI == 2) {
                    float other = __shfl_xor(v, 1);
                    if ((lane & 1) == 0) {
                        float mu = v, lv = other;
                        float el = expf(lv);
                        size_t zi = (size_t)row * 1024 + (colg >> 1);
                        float zz = mu + sqrtf(el) * EPS[zi];
                        ((unsigned char*)Cout)[zi] = f2fp8(zz * ASCALE);
                        lsum += 1.f + lv - mu * mu - el;
                    }
                } else {
                    unsigned int sb = S[(size_t)row * N + colg];
                    float sv = __builtin_amdgcn_cvt_f32_fp8(sb, 0) * (1.0f / ASCALE);
                    float d = v - sv;
                    lsum += d * d;
                }
            }
        }
    }

    if (EPI == 2 || EPI == 3) {
        __shared__ float red[4];
        float v = lsum;
#pragma unroll
        for (int o = 32; o > 0; o >>= 1) v += __shfl_down(v, o);
        if (lane == 0) red[wave] = v;
        __syncthreads();
        if (tid == 0) {
            double t = (double)red[0] + (double)red[1] +
                       (double)red[2] + (double)red[3];
            atomicAdd(accum + (EPI == 2 ? 1 : 0), t);
        }
    }
}

// ---------------------------------------------------------------------------
__global__ void finalize_kernel(const double* __restrict__ acc,
                                float* __restrict__ out) {
    if (threadIdx.x == 0)
        out[0] = (float)(acc[0] * (1.0 / (16384.0 * 4096.0)) - 0.0005 * acc[1]);
}

// ---------------------------------------------------------------------------
extern "C" void kernel_launch(void* const* d_in, const int* in_sizes, int n_in,
                              void* d_out, int out_size, void* d_ws, size_t ws_size,
                              hipStream_t stream) {
    const float* hidden = (const float*)d_in[0];
    const float* memory = (const float*)d_in[1];
    const int*   idx    = (const int*)d_in[2];
    const float* eps    = (const float*)d_in[3];
    const float* W1     = (const float*)d_in[4];
    const float* b1     = (const float*)d_in[5];
    const float* W2     = (const float*)d_in[6];
    const float* b2     = (const float*)d_in[7];
    const float* Wd1    = (const float*)d_in[8];
    const float* bd1    = (const float*)d_in[9];
    const float* Wd2    = (const float*)d_in[10];
    const float* bd2    = (const float*)d_in[11];

    char* ws = (char*)d_ws;
    double* acc            = (double*)ws;                            // 256 B
    unsigned char* s8      = (unsigned char*)(ws + 256);             // 67 MB
    unsigned char* h8      = s8   + (size_t)16384 * 4096;            // 33.6 MB
    unsigned char* z8      = h8   + (size_t)16384 * 2048;            // 16.8 MB
    unsigned char* hd8     = z8   + (size_t)16384 * 1024;            // 33.6 MB
    unsigned char* W1T     = hd8  + (size_t)16384 * 2048;
    unsigned char* W2T     = W1T  + (size_t)2048 * 4096;
    unsigned char* Wd1T    = W2T  + (size_t)2048 * 2048;
    unsigned char* Wd2T    = Wd1T + (size_t)2048 * 1024;

    init_acc<<<1, 64, 0, stream>>>(acc);

    dim3 tb(32, 8);
    transpose_cast_fp8<<<dim3(64, 128), tb, 0, stream>>>(W1, W1T, 4096, 2048, 0);
    transpose_cast_fp8<<<dim3(64, 64),  tb, 0, stream>>>(W2, W2T, 2048, 2048, 1);
    transpose_cast_fp8<<<dim3(64, 32),  tb, 0, stream>>>(Wd1, Wd1T, 1024, 2048, 0);
    transpose_cast_fp8<<<dim3(128, 64), tb, 0, stream>>>(Wd2, Wd2T, 2048, 4096, 0);

    gather_cast<<<16384, 256, 0, stream>>>(hidden, memory, idx, s8);

    // h = gelu(samples @ W1 + b1)          M=16384 N=2048 K=4096
    gemm128f8<0><<<2048, 256, 0, stream>>>(s8, W1T, b1, h8, nullptr, nullptr,
                                           nullptr, 16384, 2048, 4096, 128);
    // enc (interleaved) -> fused reparam: z fp8 + KL partials   K=2048
    gemm128f8<2><<<2048, 256, 0, stream>>>(h8, W2T, b2, z8, nullptr, eps,
                                           acc, 16384, 2048, 2048, 128);
    // hd = gelu(z @ Wd1 + bd1)             K=1024
    gemm128f8<0><<<2048, 256, 0, stream>>>(z8, Wd1T, bd1, hd8, nullptr, nullptr,
                                           nullptr, 16384, 2048, 1024, 128);
    // rec = hd @ Wd2 + bd2 ; fused recon MSE vs deq(s8)   N=4096 K=2048
    gemm128f8<3><<<4096, 256, 0, stream>>>(hd8, Wd2T, bd2, nullptr, s8,
                                           nullptr, acc, 16384, 4096, 2048, 128);

    finalize_kernel<<<1, 64, 0, stream>>>(acc, (float*)d_out);
}